// Round 1
// baseline (4305.332 us; speedup 1.0000x reference)
//
#include <hip/hip_runtime.h>
#include <hip/hip_bf16.h>
#include <cstdint>

#define TT 243
#define NJ 17
#define NB 4
#define NH 8
#define HD 64
#define CDIM 512
#define NE 4
#define NROWS (NB*TT*NJ)   // 16524
#define NBHN (NB*NH*NJ)    // 544

__device__ __forceinline__ float wave_reduce_max(float v) {
#pragma unroll
  for (int off = 32; off > 0; off >>= 1) v = fmaxf(v, __shfl_xor(v, off, 64));
  return v;
}
__device__ __forceinline__ float wave_reduce_sum(float v) {
#pragma unroll
  for (int off = 32; off > 0; off >>= 1) v += __shfl_xor(v, off, 64);
  return v;
}

// ---------------- expert gating: softmax(x @ te_w + te_b) ----------------
__global__ __launch_bounds__(256) void gates_kernel(
    const float* __restrict__ x, const float* __restrict__ te_w,
    const float* __restrict__ te_b, float* __restrict__ gates) {
  int wv = threadIdx.x >> 6;
  int lane = threadIdx.x & 63;
  int row = blockIdx.x * 4 + wv;
  if (row >= NROWS) return;
  const float* xr = x + (size_t)row * CDIM;
  float a0 = 0.f, a1 = 0.f, a2 = 0.f, a3 = 0.f;
#pragma unroll
  for (int c = 0; c < CDIM; c += 64) {
    float xv = xr[c + lane];
    float4 w = *(const float4*)(te_w + (size_t)(c + lane) * 4);
    a0 += xv * w.x; a1 += xv * w.y; a2 += xv * w.z; a3 += xv * w.w;
  }
  a0 = wave_reduce_sum(a0);
  a1 = wave_reduce_sum(a1);
  a2 = wave_reduce_sum(a2);
  a3 = wave_reduce_sum(a3);
  a0 += te_b[0]; a1 += te_b[1]; a2 += te_b[2]; a3 += te_b[3];
  float mx = fmaxf(fmaxf(a0, a1), fmaxf(a2, a3));
  float e0 = __expf(a0 - mx), e1 = __expf(a1 - mx);
  float e2 = __expf(a2 - mx), e3 = __expf(a3 - mx);
  float inv = 1.f / (e0 + e1 + e2 + e3);
  if (lane == 0) {
    float4 g = make_float4(e0 * inv, e1 * inv, e2 * inv, e3 * inv);
    *(float4*)(gates + (size_t)row * 4) = g;
  }
}

// ---------------- qkv GEMM: (16524x512)@(512x1536), scatter to (b,h,j,t,c) ----------------
__global__ __launch_bounds__(256) void qkv_gemm(
    const float* __restrict__ x, const float* __restrict__ w,
    float* __restrict__ qb, float* __restrict__ kb, float* __restrict__ vb) {
  __shared__ float As[32][68];  // [k][row], padded
  __shared__ float Bs[32][64];  // [k][col]
  int r0 = blockIdx.x * 64;
  int u0 = blockIdx.y * 64;
  int tid = threadIdx.x;
  int tx = tid & 15, ty = tid >> 4;
  float acc[4][4] = {};
  for (int k0 = 0; k0 < CDIM; k0 += 32) {
    __syncthreads();
#pragma unroll
    for (int it = 0; it < 2; ++it) {
      int fidx = tid + it * 256;
      int i = fidx >> 3, k4 = (fidx & 7) * 4;
      int r = r0 + i;
      float4 av = make_float4(0.f, 0.f, 0.f, 0.f);
      if (r < NROWS) av = *(const float4*)(x + (size_t)r * CDIM + k0 + k4);
      As[k4 + 0][i] = av.x; As[k4 + 1][i] = av.y;
      As[k4 + 2][i] = av.z; As[k4 + 3][i] = av.w;
    }
#pragma unroll
    for (int it = 0; it < 2; ++it) {
      int fidx = tid + it * 256;
      int kk = fidx >> 4, u4 = (fidx & 15) * 4;
      *(float4*)&Bs[kk][u4] = *(const float4*)(w + (size_t)(k0 + kk) * 1536 + u0 + u4);
    }
    __syncthreads();
#pragma unroll
    for (int kk = 0; kk < 32; ++kk) {
      float4 a4 = *(float4*)&As[kk][ty * 4];
      float4 b4 = *(float4*)&Bs[kk][tx * 4];
      float a[4] = {a4.x, a4.y, a4.z, a4.w};
      float b[4] = {b4.x, b4.y, b4.z, b4.w};
#pragma unroll
      for (int ii = 0; ii < 4; ++ii)
#pragma unroll
        for (int jj = 0; jj < 4; ++jj) acc[ii][jj] += a[ii] * b[jj];
    }
  }
  int m = u0 >> 9;
  int h = (u0 >> 6) & 7;
  float* dst = (m == 0) ? qb : (m == 1) ? kb : vb;
#pragma unroll
  for (int ii = 0; ii < 4; ++ii) {
    int r = r0 + ty * 4 + ii;
    if (r >= NROWS) continue;
    int bt = r / NJ, j = r % NJ;
    int b = bt / TT, t = bt % TT;
    size_t base = (((size_t)(b * NH + h) * NJ + j) * TT + t) * HD + tx * 4;
    *(float4*)(dst + base) = make_float4(acc[ii][0], acc[ii][1], acc[ii][2], acc[ii][3]);
  }
}

// ---------------- fused attention: scores -> 4 nested-window softmaxes -> gated combine -> PV ----------------
__global__ __launch_bounds__(256) void attn_kernel(
    const float* __restrict__ qb, const float* __restrict__ kb,
    const float* __restrict__ vb, const float* __restrict__ gates,
    float* __restrict__ pre) {
  __shared__ float Ss[32][244];  // scores, then combined weights r
  __shared__ float Qt[64][34];   // Q transposed [c][q]
  __shared__ float KV[64][68];   // K transposed [c][s] (score phase) / V natural [s][c] (PV phase)
  int bhn = blockIdx.x;
  int q0 = blockIdx.y * 32;
  int nq = min(32, TT - q0);
  int b = bhn / (NH * NJ);
  int hj = bhn % (NH * NJ);
  int h = hj / NJ, j = hj % NJ;
  const float* Q = qb + (size_t)bhn * TT * HD;
  const float* K = kb + (size_t)bhn * TT * HD;
  const float* V = vb + (size_t)bhn * TT * HD;
  int tid = threadIdx.x;
  int ts = tid & 15, tq = tid >> 4;

  // load Q tile transposed
#pragma unroll
  for (int it = 0; it < 2; ++it) {
    int fidx = tid + it * 256;
    int qq = fidx >> 4, c4 = (fidx & 15) * 4;
    float4 qv = make_float4(0.f, 0.f, 0.f, 0.f);
    if (q0 + qq < TT) qv = *(const float4*)(Q + (size_t)(q0 + qq) * HD + c4);
    Qt[c4 + 0][qq] = qv.x; Qt[c4 + 1][qq] = qv.y;
    Qt[c4 + 2][qq] = qv.z; Qt[c4 + 3][qq] = qv.w;
  }

  // score phase: S = Q K^T * scale
  for (int kt = 0; kt < 4; ++kt) {
    int sbase = kt * 64;
    int ns = min(64, TT - sbase);
    __syncthreads();
#pragma unroll
    for (int it = 0; it < 4; ++it) {
      int fidx = tid + it * 256;
      int ss = fidx >> 4, c4 = (fidx & 15) * 4;
      float4 kv = make_float4(0.f, 0.f, 0.f, 0.f);
      if (ss < ns) kv = *(const float4*)(K + (size_t)(sbase + ss) * HD + c4);
      KV[c4 + 0][ss] = kv.x; KV[c4 + 1][ss] = kv.y;
      KV[c4 + 2][ss] = kv.z; KV[c4 + 3][ss] = kv.w;
    }
    __syncthreads();
    float acc[2][4] = {};
    for (int c = 0; c < 64; ++c) {
      float2 qv = *(float2*)&Qt[c][tq * 2];
      float4 k4 = *(float4*)&KV[c][ts * 4];
      float qa[2] = {qv.x, qv.y};
      float ka[4] = {k4.x, k4.y, k4.z, k4.w};
#pragma unroll
      for (int i = 0; i < 2; ++i)
#pragma unroll
        for (int jj = 0; jj < 4; ++jj) acc[i][jj] += qa[i] * ka[jj];
    }
#pragma unroll
    for (int i = 0; i < 2; ++i)
#pragma unroll
      for (int jj = 0; jj < 4; ++jj) {
        int s = sbase + ts * 4 + jj;
        if (s < TT) Ss[tq * 2 + i][s] = acc[i][jj] * 0.125f;
      }
  }
  __syncthreads();

  // softmax over 4 nested windows + gated combine into one weight vector r
  int wv = tid >> 6, lane = tid & 63;
  for (int q = wv; q < nq; q += 4) {
    int t = q0 + q;
    float sc[4];
#pragma unroll
    for (int r = 0; r < 4; ++r) {
      int s = lane + 64 * r;
      sc[r] = (s < TT) ? Ss[q][s] : -1e30f;
    }
    const int wins[4] = {9, 27, 81, 243};
    float m[4], l[4];
#pragma unroll
    for (int e = 0; e < 4; ++e) {
      int w = wins[e];
      int t0 = (t / w) * w;
      float mm = -1e30f;
#pragma unroll
      for (int r = 0; r < 4; ++r) {
        int s = lane + 64 * r;
        if (s >= t0 && s < t0 + w) mm = fmaxf(mm, sc[r]);
      }
      mm = wave_reduce_max(mm);
      float su = 0.f;
#pragma unroll
      for (int r = 0; r < 4; ++r) {
        int s = lane + 64 * r;
        if (s >= t0 && s < t0 + w) su += __expf(sc[r] - mm);
      }
      su = wave_reduce_sum(su);
      m[e] = mm; l[e] = su;
    }
    float4 g = *(const float4*)(gates + (size_t)((b * TT + t) * NJ + j) * 4);
    float M = m[3];
    float c0 = g.x * __expf(M - m[0]) / l[0];
    float c1 = g.y * __expf(M - m[1]) / l[1];
    float c2 = g.z * __expf(M - m[2]) / l[2];
    float c3 = g.w * __expf(M - m[3]) / l[3];
#pragma unroll
    for (int r = 0; r < 4; ++r) {
      int s = lane + 64 * r;
      if (s < TT) {
        float cw = c3;
        if (s / 81 == t / 81) cw += c2;
        if (s / 27 == t / 27) cw += c1;
        if (s / 9 == t / 9) cw += c0;
        Ss[q][s] = __expf(sc[r] - M) * cw;
      }
    }
  }

  // PV phase: O = R @ V
  float oacc[2][4] = {};
  for (int kt = 0; kt < 4; ++kt) {
    int sbase = kt * 64;
    int ns = min(64, TT - sbase);
    __syncthreads();
#pragma unroll
    for (int it = 0; it < 4; ++it) {
      int fidx = tid + it * 256;
      int ss = fidx >> 4, c4 = (fidx & 15) * 4;
      float4 vv = make_float4(0.f, 0.f, 0.f, 0.f);
      if (ss < ns) vv = *(const float4*)(V + (size_t)(sbase + ss) * HD + c4);
      *(float4*)&KV[ss][c4] = vv;
    }
    __syncthreads();
    for (int s = 0; s < ns; ++s) {
      float r0v = Ss[tq * 2 + 0][sbase + s];
      float r1v = Ss[tq * 2 + 1][sbase + s];
      float4 vv = *(float4*)&KV[s][ts * 4];
      float va[4] = {vv.x, vv.y, vv.z, vv.w};
#pragma unroll
      for (int jj = 0; jj < 4; ++jj) {
        oacc[0][jj] += r0v * va[jj];
        oacc[1][jj] += r1v * va[jj];
      }
    }
  }
#pragma unroll
  for (int i = 0; i < 2; ++i) {
    int q = tq * 2 + i;
    if (q < nq) {
      int t = q0 + q;
      size_t row = (size_t)(b * TT + t) * NJ + j;
      *(float4*)(pre + row * CDIM + h * HD + ts * 4) =
          make_float4(oacc[i][0], oacc[i][1], oacc[i][2], oacc[i][3]);
    }
  }
}

// ---------------- output projection GEMM + bias ----------------
__global__ __launch_bounds__(256) void proj_gemm(
    const float* __restrict__ pre, const float* __restrict__ w,
    const float* __restrict__ bias, float* __restrict__ out) {
  __shared__ float As[32][68];
  __shared__ float Bs[32][64];
  int r0 = blockIdx.x * 64;
  int u0 = blockIdx.y * 64;
  int tid = threadIdx.x;
  int tx = tid & 15, ty = tid >> 4;
  float acc[4][4] = {};
  for (int k0 = 0; k0 < CDIM; k0 += 32) {
    __syncthreads();
#pragma unroll
    for (int it = 0; it < 2; ++it) {
      int fidx = tid + it * 256;
      int i = fidx >> 3, k4 = (fidx & 7) * 4;
      int r = r0 + i;
      float4 av = make_float4(0.f, 0.f, 0.f, 0.f);
      if (r < NROWS) av = *(const float4*)(pre + (size_t)r * CDIM + k0 + k4);
      As[k4 + 0][i] = av.x; As[k4 + 1][i] = av.y;
      As[k4 + 2][i] = av.z; As[k4 + 3][i] = av.w;
    }
#pragma unroll
    for (int it = 0; it < 2; ++it) {
      int fidx = tid + it * 256;
      int kk = fidx >> 4, u4 = (fidx & 15) * 4;
      *(float4*)&Bs[kk][u4] = *(const float4*)(w + (size_t)(k0 + kk) * CDIM + u0 + u4);
    }
    __syncthreads();
#pragma unroll
    for (int kk = 0; kk < 32; ++kk) {
      float4 a4 = *(float4*)&As[kk][ty * 4];
      float4 b4 = *(float4*)&Bs[kk][tx * 4];
      float a[4] = {a4.x, a4.y, a4.z, a4.w};
      float b[4] = {b4.x, b4.y, b4.z, b4.w};
#pragma unroll
      for (int ii = 0; ii < 4; ++ii)
#pragma unroll
        for (int jj = 0; jj < 4; ++jj) acc[ii][jj] += a[ii] * b[jj];
    }
  }
  float4 bb = *(const float4*)(bias + u0 + tx * 4);
  float bbv[4] = {bb.x, bb.y, bb.z, bb.w};
#pragma unroll
  for (int ii = 0; ii < 4; ++ii) {
    int r = r0 + ty * 4 + ii;
    if (r >= NROWS) continue;
    *(float4*)(out + (size_t)r * CDIM + u0 + tx * 4) =
        make_float4(acc[ii][0] + bbv[0], acc[ii][1] + bbv[1],
                    acc[ii][2] + bbv[2], acc[ii][3] + bbv[3]);
  }
}

extern "C" void kernel_launch(void* const* d_in, const int* in_sizes, int n_in,
                              void* d_out, int out_size, void* d_ws, size_t ws_size,
                              hipStream_t stream) {
  (void)in_sizes; (void)n_in; (void)out_size; (void)ws_size;
  const float* x      = (const float*)d_in[0];
  const float* qkv_w  = (const float*)d_in[1];
  const float* proj_w = (const float*)d_in[2];
  const float* proj_b = (const float*)d_in[3];
  const float* te_w   = (const float*)d_in[4];
  const float* te_b   = (const float*)d_in[5];

  float* ws = (float*)d_ws;
  const size_t per = (size_t)NBHN * TT * HD;  // 8,460,288
  float* qb    = ws;
  float* kb    = qb + per;
  float* vb    = kb + per;
  float* gates = vb + per;
  float* pre   = gates + (size_t)NROWS * 4;
  float* out   = (float*)d_out;

  hipLaunchKernelGGL(gates_kernel, dim3((NROWS + 3) / 4), dim3(256), 0, stream,
                     x, te_w, te_b, gates);
  hipLaunchKernelGGL(qkv_gemm, dim3(259, 24), dim3(256), 0, stream,
                     x, qkv_w, qb, kb, vb);
  hipLaunchKernelGGL(attn_kernel, dim3(NBHN, 8), dim3(256), 0, stream,
                     qb, kb, vb, gates, pre);
  hipLaunchKernelGGL(proj_gemm, dim3(259, 8), dim3(256), 0, stream,
                     pre, proj_w, proj_b, out);
}

// Round 2
// 941.489 us; speedup vs baseline: 4.5729x; 4.5729x over previous
//
#include <hip/hip_runtime.h>
#include <hip/hip_bf16.h>
#include <cstdint>

#define TT 243
#define NJ 17
#define NB 4
#define NH 8
#define HD 64
#define CDIM 512
#define NE 4
#define NROWS (NB*TT*NJ)   // 16524
#define NBHN (NB*NH*NJ)    // 544

__device__ __forceinline__ float wave_reduce_max(float v) {
#pragma unroll
  for (int off = 32; off > 0; off >>= 1) v = fmaxf(v, __shfl_xor(v, off, 64));
  return v;
}
__device__ __forceinline__ float wave_reduce_sum(float v) {
#pragma unroll
  for (int off = 32; off > 0; off >>= 1) v += __shfl_xor(v, off, 64);
  return v;
}

// ---------------- expert gating: softmax(x @ te_w + te_b) ----------------
__global__ __launch_bounds__(256) void gates_kernel(
    const float* __restrict__ x, const float* __restrict__ te_w,
    const float* __restrict__ te_b, float* __restrict__ gates) {
  int wv = threadIdx.x >> 6;
  int lane = threadIdx.x & 63;
  int row = blockIdx.x * 4 + wv;
  if (row >= NROWS) return;
  const float* xr = x + (size_t)row * CDIM;
  float a0 = 0.f, a1 = 0.f, a2 = 0.f, a3 = 0.f;
#pragma unroll
  for (int c = 0; c < CDIM; c += 64) {
    float xv = xr[c + lane];
    float4 w = *(const float4*)(te_w + (size_t)(c + lane) * 4);
    a0 += xv * w.x; a1 += xv * w.y; a2 += xv * w.z; a3 += xv * w.w;
  }
  a0 = wave_reduce_sum(a0);
  a1 = wave_reduce_sum(a1);
  a2 = wave_reduce_sum(a2);
  a3 = wave_reduce_sum(a3);
  a0 += te_b[0]; a1 += te_b[1]; a2 += te_b[2]; a3 += te_b[3];
  float mx = fmaxf(fmaxf(a0, a1), fmaxf(a2, a3));
  float e0 = __expf(a0 - mx), e1 = __expf(a1 - mx);
  float e2 = __expf(a2 - mx), e3 = __expf(a3 - mx);
  float inv = 1.f / (e0 + e1 + e2 + e3);
  if (lane == 0) {
    float4 g = make_float4(e0 * inv, e1 * inv, e2 * inv, e3 * inv);
    *(float4*)(gates + (size_t)row * 4) = g;
  }
}

// ---------------- qkv GEMM: (16524x512)@(512x1536), scatter to (b,h,j,t,c) ----------------
__global__ __launch_bounds__(256) void qkv_gemm(
    const float* __restrict__ x, const float* __restrict__ w,
    float* __restrict__ qb, float* __restrict__ kb, float* __restrict__ vb) {
  __shared__ float As[32][68];  // [k][row], padded
  __shared__ float Bs[32][64];  // [k][col]
  int r0 = blockIdx.x * 64;
  int u0 = blockIdx.y * 64;
  int tid = threadIdx.x;
  int tx = tid & 15, ty = tid >> 4;
  float acc[4][4] = {};
  for (int k0 = 0; k0 < CDIM; k0 += 32) {
    __syncthreads();
#pragma unroll
    for (int it = 0; it < 2; ++it) {
      int fidx = tid + it * 256;
      int i = fidx >> 3, k4 = (fidx & 7) * 4;
      int r = r0 + i;
      float4 av = make_float4(0.f, 0.f, 0.f, 0.f);
      if (r < NROWS) av = *(const float4*)(x + (size_t)r * CDIM + k0 + k4);
      As[k4 + 0][i] = av.x; As[k4 + 1][i] = av.y;
      As[k4 + 2][i] = av.z; As[k4 + 3][i] = av.w;
    }
#pragma unroll
    for (int it = 0; it < 2; ++it) {
      int fidx = tid + it * 256;
      int kk = fidx >> 4, u4 = (fidx & 15) * 4;
      *(float4*)&Bs[kk][u4] = *(const float4*)(w + (size_t)(k0 + kk) * 1536 + u0 + u4);
    }
    __syncthreads();
#pragma unroll 8
    for (int kk = 0; kk < 32; ++kk) {
      float4 a4 = *(float4*)&As[kk][ty * 4];
      float4 b4 = *(float4*)&Bs[kk][tx * 4];
      float a[4] = {a4.x, a4.y, a4.z, a4.w};
      float b[4] = {b4.x, b4.y, b4.z, b4.w};
#pragma unroll
      for (int ii = 0; ii < 4; ++ii)
#pragma unroll
        for (int jj = 0; jj < 4; ++jj) acc[ii][jj] += a[ii] * b[jj];
    }
  }
  int m = u0 >> 9;
  int h = (u0 >> 6) & 7;
  float* dst = (m == 0) ? qb : (m == 1) ? kb : vb;
#pragma unroll
  for (int ii = 0; ii < 4; ++ii) {
    int r = r0 + ty * 4 + ii;
    if (r >= NROWS) continue;
    int bt = r / NJ, j = r % NJ;
    int b = bt / TT, t = bt % TT;
    size_t base = (((size_t)(b * NH + h) * NJ + j) * TT + t) * HD + tx * 4;
    *(float4*)(dst + base) = make_float4(acc[ii][0], acc[ii][1], acc[ii][2], acc[ii][3]);
  }
}

// ---------------- fused attention: scores -> 4 nested-window softmaxes -> gated combine -> PV ----------------
__global__ __launch_bounds__(256, 2) void attn_kernel(
    const float* __restrict__ qb, const float* __restrict__ kb,
    const float* __restrict__ vb, const float* __restrict__ gates,
    float* __restrict__ pre) {
  __shared__ float Ss[32][244];  // scores, then combined weights r
  __shared__ float Qt[64][34];   // Q transposed [c][q]
  __shared__ float KV[64][68];   // K transposed [c][s] (score phase) / V natural [s][c] (PV phase)
  int bhn = blockIdx.x;
  int q0 = blockIdx.y * 32;
  int nq = min(32, TT - q0);
  int b = bhn / (NH * NJ);
  int hj = bhn % (NH * NJ);
  int h = hj / NJ, j = hj % NJ;
  const float* Q = qb + (size_t)bhn * TT * HD;
  const float* K = kb + (size_t)bhn * TT * HD;
  const float* V = vb + (size_t)bhn * TT * HD;
  int tid = threadIdx.x;
  int ts = tid & 15, tq = tid >> 4;

  // load Q tile transposed
#pragma unroll
  for (int it = 0; it < 2; ++it) {
    int fidx = tid + it * 256;
    int qq = fidx >> 4, c4 = (fidx & 15) * 4;
    float4 qv = make_float4(0.f, 0.f, 0.f, 0.f);
    if (q0 + qq < TT) qv = *(const float4*)(Q + (size_t)(q0 + qq) * HD + c4);
    Qt[c4 + 0][qq] = qv.x; Qt[c4 + 1][qq] = qv.y;
    Qt[c4 + 2][qq] = qv.z; Qt[c4 + 3][qq] = qv.w;
  }

  // score phase: S = Q K^T * scale
  for (int kt = 0; kt < 4; ++kt) {
    int sbase = kt * 64;
    int ns = min(64, TT - sbase);
    __syncthreads();
#pragma unroll
    for (int it = 0; it < 4; ++it) {
      int fidx = tid + it * 256;
      int ss = fidx >> 4, c4 = (fidx & 15) * 4;
      float4 kv = make_float4(0.f, 0.f, 0.f, 0.f);
      if (ss < ns) kv = *(const float4*)(K + (size_t)(sbase + ss) * HD + c4);
      KV[c4 + 0][ss] = kv.x; KV[c4 + 1][ss] = kv.y;
      KV[c4 + 2][ss] = kv.z; KV[c4 + 3][ss] = kv.w;
    }
    __syncthreads();
    float acc[2][4] = {};
#pragma unroll 8
    for (int c = 0; c < 64; ++c) {
      float2 qv = *(float2*)&Qt[c][tq * 2];
      float4 k4 = *(float4*)&KV[c][ts * 4];
      float qa[2] = {qv.x, qv.y};
      float ka[4] = {k4.x, k4.y, k4.z, k4.w};
#pragma unroll
      for (int i = 0; i < 2; ++i)
#pragma unroll
        for (int jj = 0; jj < 4; ++jj) acc[i][jj] += qa[i] * ka[jj];
    }
#pragma unroll
    for (int i = 0; i < 2; ++i)
#pragma unroll
      for (int jj = 0; jj < 4; ++jj) {
        int s = sbase + ts * 4 + jj;
        if (s < TT) Ss[tq * 2 + i][s] = acc[i][jj] * 0.125f;
      }
  }
  __syncthreads();

  // softmax over 4 nested windows + gated combine into one weight vector r
  int wv = tid >> 6, lane = tid & 63;
  for (int q = wv; q < nq; q += 4) {
    int t = q0 + q;
    float sc[4];
#pragma unroll
    for (int r = 0; r < 4; ++r) {
      int s = lane + 64 * r;
      sc[r] = (s < TT) ? Ss[q][s] : -1e30f;
    }
    const int wins[4] = {9, 27, 81, 243};
    float m[4], l[4];
#pragma unroll
    for (int e = 0; e < 4; ++e) {
      int w = wins[e];
      int t0 = (t / w) * w;
      float mm = -1e30f;
#pragma unroll
      for (int r = 0; r < 4; ++r) {
        int s = lane + 64 * r;
        if (s >= t0 && s < t0 + w) mm = fmaxf(mm, sc[r]);
      }
      mm = wave_reduce_max(mm);
      float su = 0.f;
#pragma unroll
      for (int r = 0; r < 4; ++r) {
        int s = lane + 64 * r;
        if (s >= t0 && s < t0 + w) su += __expf(sc[r] - mm);
      }
      su = wave_reduce_sum(su);
      m[e] = mm; l[e] = su;
    }
    float4 g = *(const float4*)(gates + (size_t)((b * TT + t) * NJ + j) * 4);
    float M = m[3];
    float c0 = g.x * __expf(M - m[0]) / l[0];
    float c1 = g.y * __expf(M - m[1]) / l[1];
    float c2 = g.z * __expf(M - m[2]) / l[2];
    float c3 = g.w * __expf(M - m[3]) / l[3];
#pragma unroll
    for (int r = 0; r < 4; ++r) {
      int s = lane + 64 * r;
      if (s < TT) {
        float cw = c3;
        if (s / 81 == t / 81) cw += c2;
        if (s / 27 == t / 27) cw += c1;
        if (s / 9 == t / 9) cw += c0;
        Ss[q][s] = __expf(sc[r] - M) * cw;
      }
    }
  }

  // PV phase: O = R @ V
  float oacc[2][4] = {};
  for (int kt = 0; kt < 4; ++kt) {
    int sbase = kt * 64;
    int ns = min(64, TT - sbase);
    __syncthreads();
#pragma unroll
    for (int it = 0; it < 4; ++it) {
      int fidx = tid + it * 256;
      int ss = fidx >> 4, c4 = (fidx & 15) * 4;
      float4 vv = make_float4(0.f, 0.f, 0.f, 0.f);
      if (ss < ns) vv = *(const float4*)(V + (size_t)(sbase + ss) * HD + c4);
      *(float4*)&KV[ss][c4] = vv;
    }
    __syncthreads();
#pragma unroll 8
    for (int s = 0; s < ns; ++s) {
      float r0v = Ss[tq * 2 + 0][sbase + s];
      float r1v = Ss[tq * 2 + 1][sbase + s];
      float4 vv = *(float4*)&KV[s][ts * 4];
      float va[4] = {vv.x, vv.y, vv.z, vv.w};
#pragma unroll
      for (int jj = 0; jj < 4; ++jj) {
        oacc[0][jj] += r0v * va[jj];
        oacc[1][jj] += r1v * va[jj];
      }
    }
  }
#pragma unroll
  for (int i = 0; i < 2; ++i) {
    int q = tq * 2 + i;
    if (q < nq) {
      int t = q0 + q;
      size_t row = (size_t)(b * TT + t) * NJ + j;
      *(float4*)(pre + row * CDIM + h * HD + ts * 4) =
          make_float4(oacc[i][0], oacc[i][1], oacc[i][2], oacc[i][3]);
    }
  }
}

// ---------------- output projection GEMM + bias ----------------
__global__ __launch_bounds__(256) void proj_gemm(
    const float* __restrict__ pre, const float* __restrict__ w,
    const float* __restrict__ bias, float* __restrict__ out) {
  __shared__ float As[32][68];
  __shared__ float Bs[32][64];
  int r0 = blockIdx.x * 64;
  int u0 = blockIdx.y * 64;
  int tid = threadIdx.x;
  int tx = tid & 15, ty = tid >> 4;
  float acc[4][4] = {};
  for (int k0 = 0; k0 < CDIM; k0 += 32) {
    __syncthreads();
#pragma unroll
    for (int it = 0; it < 2; ++it) {
      int fidx = tid + it * 256;
      int i = fidx >> 3, k4 = (fidx & 7) * 4;
      int r = r0 + i;
      float4 av = make_float4(0.f, 0.f, 0.f, 0.f);
      if (r < NROWS) av = *(const float4*)(pre + (size_t)r * CDIM + k0 + k4);
      As[k4 + 0][i] = av.x; As[k4 + 1][i] = av.y;
      As[k4 + 2][i] = av.z; As[k4 + 3][i] = av.w;
    }
#pragma unroll
    for (int it = 0; it < 2; ++it) {
      int fidx = tid + it * 256;
      int kk = fidx >> 4, u4 = (fidx & 15) * 4;
      *(float4*)&Bs[kk][u4] = *(const float4*)(w + (size_t)(k0 + kk) * CDIM + u0 + u4);
    }
    __syncthreads();
#pragma unroll 8
    for (int kk = 0; kk < 32; ++kk) {
      float4 a4 = *(float4*)&As[kk][ty * 4];
      float4 b4 = *(float4*)&Bs[kk][tx * 4];
      float a[4] = {a4.x, a4.y, a4.z, a4.w};
      float b[4] = {b4.x, b4.y, b4.z, b4.w};
#pragma unroll
      for (int ii = 0; ii < 4; ++ii)
#pragma unroll
        for (int jj = 0; jj < 4; ++jj) acc[ii][jj] += a[ii] * b[jj];
    }
  }
  float4 bb = *(const float4*)(bias + u0 + tx * 4);
  float bbv[4] = {bb.x, bb.y, bb.z, bb.w};
#pragma unroll
  for (int ii = 0; ii < 4; ++ii) {
    int r = r0 + ty * 4 + ii;
    if (r >= NROWS) continue;
    *(float4*)(out + (size_t)r * CDIM + u0 + tx * 4) =
        make_float4(acc[ii][0] + bbv[0], acc[ii][1] + bbv[1],
                    acc[ii][2] + bbv[2], acc[ii][3] + bbv[3]);
  }
}

extern "C" void kernel_launch(void* const* d_in, const int* in_sizes, int n_in,
                              void* d_out, int out_size, void* d_ws, size_t ws_size,
                              hipStream_t stream) {
  (void)in_sizes; (void)n_in; (void)out_size; (void)ws_size;
  const float* x      = (const float*)d_in[0];
  const float* qkv_w  = (const float*)d_in[1];
  const float* proj_w = (const float*)d_in[2];
  const float* proj_b = (const float*)d_in[3];
  const float* te_w   = (const float*)d_in[4];
  const float* te_b   = (const float*)d_in[5];

  float* ws = (float*)d_ws;
  const size_t per = (size_t)NBHN * TT * HD;  // 8,460,288
  float* qb    = ws;
  float* kb    = qb + per;
  float* vb    = kb + per;
  float* gates = vb + per;
  float* pre   = gates + (size_t)NROWS * 4;
  float* out   = (float*)d_out;

  hipLaunchKernelGGL(gates_kernel, dim3((NROWS + 3) / 4), dim3(256), 0, stream,
                     x, te_w, te_b, gates);
  hipLaunchKernelGGL(qkv_gemm, dim3(259, 24), dim3(256), 0, stream,
                     x, qkv_w, qb, kb, vb);
  hipLaunchKernelGGL(attn_kernel, dim3(NBHN, 8), dim3(256), 0, stream,
                     qb, kb, vb, gates, pre);
  hipLaunchKernelGGL(proj_gemm, dim3(259, 8), dim3(256), 0, stream,
                     pre, proj_w, proj_b, out);
}

// Round 3
// 315.515 us; speedup vs baseline: 13.6454x; 2.9840x over previous
//
#include <hip/hip_runtime.h>
#include <hip/hip_bf16.h>
#include <cstdint>

#define TT 243
#define NJ 17
#define NB 4
#define NH 8
#define HD 64
#define CDIM 512
#define NROWS (NB*TT*NJ)   // 16524
#define NBHN (NB*NH*NJ)    // 544

typedef unsigned short u16;
typedef __attribute__((ext_vector_type(8))) short short8;
typedef __attribute__((ext_vector_type(4))) float f32x4;

#define MFMA16(a, b, c) __builtin_amdgcn_mfma_f32_16x16x32_bf16((a), (b), (c), 0, 0, 0)

__device__ __forceinline__ void gl_lds16(const void* g, void* l) {
  __builtin_amdgcn_global_load_lds(
      (const __attribute__((address_space(1))) void*)g,
      (__attribute__((address_space(3))) void*)l, 16, 0, 0);
}

__device__ __forceinline__ u16 f2bf(float f) {
  union { float f; unsigned u; } v; v.f = f;
  unsigned r = v.u + 0x7FFFu + ((v.u >> 16) & 1u);
  return (u16)(r >> 16);
}

__device__ __forceinline__ float wave_reduce_sum(float v) {
#pragma unroll
  for (int off = 32; off > 0; off >>= 1) v += __shfl_xor(v, off, 64);
  return v;
}

// ---------------- prep: fp32 -> bf16 copy of x ----------------
__global__ __launch_bounds__(256) void conv_x(const float* __restrict__ x,
                                              u16* __restrict__ xb, int n4) {
  int i = blockIdx.x * 256 + threadIdx.x;
  if (i >= n4) return;
  float4 v = ((const float4*)x)[i];
  ushort4 o;
  o.x = f2bf(v.x); o.y = f2bf(v.y); o.z = f2bf(v.z); o.w = f2bf(v.w);
  ((ushort4*)xb)[i] = o;
}

// ---------------- prep: transpose fp32 [K][N] -> bf16 [N][K] ----------------
__global__ __launch_bounds__(256) void trans_w(const float* __restrict__ in,
                                               u16* __restrict__ out, int K, int N) {
  __shared__ float tile[32][33];
  int n0 = blockIdx.x * 32, k0 = blockIdx.y * 32;
  int tx = threadIdx.x & 31, ty = threadIdx.x >> 5;
#pragma unroll
  for (int p = 0; p < 4; ++p)
    tile[ty + p * 8][tx] = in[(size_t)(k0 + ty + p * 8) * N + n0 + tx];
  __syncthreads();
#pragma unroll
  for (int p = 0; p < 4; ++p)
    out[(size_t)(n0 + ty + p * 8) * K + k0 + tx] = f2bf(tile[tx][ty + p * 8]);
}

// ---------------- expert gating: softmax(x @ te_w + te_b) ----------------
__global__ __launch_bounds__(256) void gates_kernel(
    const float* __restrict__ x, const float* __restrict__ te_w,
    const float* __restrict__ te_b, float* __restrict__ gates) {
  int wv = threadIdx.x >> 6;
  int lane = threadIdx.x & 63;
  int row = blockIdx.x * 4 + wv;
  if (row >= NROWS) return;
  const float* xr = x + (size_t)row * CDIM;
  float a0 = 0.f, a1 = 0.f, a2 = 0.f, a3 = 0.f;
#pragma unroll
  for (int c = 0; c < CDIM; c += 64) {
    float xv = xr[c + lane];
    float4 w = *(const float4*)(te_w + (size_t)(c + lane) * 4);
    a0 += xv * w.x; a1 += xv * w.y; a2 += xv * w.z; a3 += xv * w.w;
  }
  a0 = wave_reduce_sum(a0);
  a1 = wave_reduce_sum(a1);
  a2 = wave_reduce_sum(a2);
  a3 = wave_reduce_sum(a3);
  a0 += te_b[0]; a1 += te_b[1]; a2 += te_b[2]; a3 += te_b[3];
  float mx = fmaxf(fmaxf(a0, a1), fmaxf(a2, a3));
  float e0 = __expf(a0 - mx), e1 = __expf(a1 - mx);
  float e2 = __expf(a2 - mx), e3 = __expf(a3 - mx);
  float inv = 1.f / (e0 + e1 + e2 + e3);
  if (lane == 0) {
    float4 g = make_float4(e0 * inv, e1 * inv, e2 * inv, e3 * inv);
    *(float4*)(gates + (size_t)row * 4) = g;
  }
}

// ---------------- qkv GEMM (bf16 MFMA): C = xb[16524x512] @ wt^T[512x1536] ----------------
// q,k -> qkvb linear [row][1536] bf16 ; v -> vb [bhn][64][256] bf16 (t-major, padded)
__global__ __launch_bounds__(256) void qkv_gemm(
    const u16* __restrict__ xb, const u16* __restrict__ wt,
    u16* __restrict__ qkvb, u16* __restrict__ vb) {
  __shared__ u16 Al[128 * 32];
  __shared__ u16 Bl[128 * 32];
  int tid = threadIdx.x;
  int w = tid >> 6, l = tid & 63;
  int c16 = tid & 15, g4 = (tid >> 4) & 3;
  int r0 = blockIdx.x * 128, n0 = blockIdx.y * 128;
  int wm = w & 1, wn = w >> 1;
  f32x4 acc[4][4] = {};
  for (int k0 = 0; k0 < CDIM; k0 += 32) {
    __syncthreads();
#pragma unroll
    for (int it = 0; it < 2; ++it) {
      int F = it * 256 + w * 64 + l;   // chunk 0..511
      int row = F >> 2, c8 = F & 3;
      int gr = r0 + row; gr = gr < NROWS ? gr : NROWS - 1;
      gl_lds16(xb + (size_t)gr * 512 + k0 + c8 * 8,
               Al + (size_t)(it * 256 + w * 64) * 8);
      gl_lds16(wt + (size_t)(n0 + row) * 512 + k0 + c8 * 8,
               Bl + (size_t)(it * 256 + w * 64) * 8);
    }
    __syncthreads();
    short8 af[4], bf[4];
#pragma unroll
    for (int i = 0; i < 4; ++i)
      af[i] = *(const short8*)(Al + ((wm * 64 + i * 16 + c16) * 32 + g4 * 8));
#pragma unroll
    for (int j = 0; j < 4; ++j)
      bf[j] = *(const short8*)(Bl + ((wn * 64 + j * 16 + c16) * 32 + g4 * 8));
#pragma unroll
    for (int i = 0; i < 4; ++i)
#pragma unroll
      for (int j = 0; j < 4; ++j)
        acc[i][j] = MFMA16(af[i], bf[j], acc[i][j]);
  }
#pragma unroll
  for (int i = 0; i < 4; ++i) {
#pragma unroll
    for (int r = 0; r < 4; ++r) {
      int row = r0 + wm * 64 + i * 16 + g4 * 4 + r;
      if (row >= NROWS) continue;
      int bb = row / (TT * NJ);
      int rem = row - bb * (TT * NJ);
      int t = rem / NJ;
      int jj = rem - t * NJ;
#pragma unroll
      for (int jt = 0; jt < 4; ++jt) {
        int col = n0 + wn * 64 + jt * 16 + c16;
        u16 bv = f2bf(acc[i][jt][r]);
        int m = col >> 9;
        if (m < 2) {
          qkvb[(size_t)row * 1536 + col] = bv;
        } else {
          int h = (col >> 6) & 7;
          int c = col & 63;
          int bhn = (bb * NH + h) * NJ + jj;
          vb[((size_t)bhn * 64 + c) * 256 + t] = bv;
        }
      }
    }
  }
}

// ---------------- fused attention (bf16 MFMA) ----------------
// grid (544, 4): one (b,h,j), 64-query tile. LDS 64KB union:
//  phase1: K [0,16384) elems [256][64] swizzled; Q [16384,20480) [64][64] swizzled
//  phase2: R [0,16384) [64][256] swizzled;      V [16384,32768) [64][256] swizzled
__global__ __launch_bounds__(256) void attn_kernel(
    const u16* __restrict__ qkvb, const u16* __restrict__ vb,
    const float* __restrict__ gates, u16* __restrict__ preb) {
  __shared__ u16 L[32768];
  int bhn = blockIdx.x;
  int q0 = blockIdx.y * 64;
  int b = bhn / (NH * NJ);
  int hj = bhn - b * (NH * NJ);
  int h = hj / NJ, j = hj - (hj / NJ) * NJ;
  int tid = threadIdx.x;
  int w = tid >> 6, l = tid & 63;
  int c16 = tid & 15, g4 = (tid >> 4) & 3;
  int qw = w * 16;

  // ---- stage K (8 calls) + Q (2 calls) via global_load_lds, xor-swizzled chunks
#pragma unroll
  for (int it = 0; it < 8; ++it) {
    int F = it * 256 + w * 64 + l;          // 0..2047
    int s = F >> 3;
    int c8 = (F & 7) ^ (s & 7);
    int sg = s < TT ? s : TT - 1;
    gl_lds16(qkvb + ((size_t)(b * TT + sg) * NJ + j) * 1536 + 512 + h * 64 + c8 * 8,
             L + (size_t)(it * 256 + w * 64) * 8);
  }
#pragma unroll
  for (int it = 0; it < 2; ++it) {
    int F = it * 256 + w * 64 + l;          // 0..511
    int q = F >> 3;
    int c8 = (F & 7) ^ (q & 7);
    int t = q0 + q; int tg = t < TT ? t : TT - 1;
    gl_lds16(qkvb + ((size_t)(b * TT + tg) * NJ + j) * 1536 + 0 + h * 64 + c8 * 8,
             L + 16384 + (size_t)(it * 256 + w * 64) * 8);
  }
  __syncthreads();

  // ---- scores: S[16q][256s] per wave, C-fragments
  short8 aq[2];
#pragma unroll
  for (int hh = 0; hh < 2; ++hh) {
    int q = qw + c16;
    aq[hh] = *(const short8*)(L + 16384 + q * 64 + ((hh * 4 + g4) ^ (q & 7)) * 8);
  }
  f32x4 acc[16];
#pragma unroll
  for (int st = 0; st < 16; ++st) acc[st] = (f32x4)(0.f);
#pragma unroll
  for (int st = 0; st < 16; ++st) {
    int s = st * 16 + c16;
#pragma unroll
    for (int hh = 0; hh < 2; ++hh) {
      short8 bk = *(const short8*)(L + s * 64 + ((hh * 4 + g4) ^ (s & 7)) * 8);
      acc[st] = MFMA16(aq[hh], bk, acc[st]);
    }
  }
  __syncthreads();   // all K/Q reads complete before LDS reuse

  // ---- stage V [64c][256s] into upper half (overlaps softmax below)
#pragma unroll
  for (int it = 0; it < 8; ++it) {
    int F = it * 256 + w * 64 + l;          // 0..2047
    int c = F >> 5;
    int slot = F & 31;
    int c8 = (slot & 24) | ((slot & 7) ^ (c & 7));
    gl_lds16(vb + ((size_t)bhn * 64 + c) * 256 + c8 * 8,
             L + 16384 + (size_t)(it * 256 + w * 64) * 8);
  }

  // ---- softmax over nested windows, in registers
  int tr[4], t9[4], t27[4], t81[4];
#pragma unroll
  for (int r = 0; r < 4; ++r) {
    tr[r] = q0 + qw + g4 * 4 + r;
    t9[r] = tr[r] / 9; t27[r] = t9[r] / 3; t81[r] = t27[r] / 3;
  }
  // scale + mask
#pragma unroll
  for (int st = 0; st < 16; ++st) {
    int s = st * 16 + c16;
#pragma unroll
    for (int r = 0; r < 4; ++r) {
      float v = acc[st][r] * 0.125f;
      acc[st][r] = (s < TT) ? v : -1e30f;
    }
  }
  // global row max
  float M[4];
#pragma unroll
  for (int r = 0; r < 4; ++r) {
    float m = -1e30f;
#pragma unroll
    for (int st = 0; st < 16; ++st) m = fmaxf(m, acc[st][r]);
    m = fmaxf(m, __shfl_xor(m, 1, 64));
    m = fmaxf(m, __shfl_xor(m, 2, 64));
    m = fmaxf(m, __shfl_xor(m, 4, 64));
    m = fmaxf(m, __shfl_xor(m, 8, 64));
    M[r] = m;
  }
  // exp
#pragma unroll
  for (int st = 0; st < 16; ++st)
#pragma unroll
    for (int r = 0; r < 4; ++r) acc[st][r] = __expf(acc[st][r] - M[r]);
  // window sums (windows nested; masked s>=243 contribute exp(-huge)=0)
  int s9[16], s27[16], s81[16];
#pragma unroll
  for (int st = 0; st < 16; ++st) {
    int s = st * 16 + c16;
    s9[st] = s / 9; s27[st] = s9[st] / 3; s81[st] = s27[st] / 3;
  }
  float l9[4], l27[4], l81[4], l243[4];
#pragma unroll
  for (int r = 0; r < 4; ++r) { l9[r] = 0.f; l27[r] = 0.f; l81[r] = 0.f; l243[r] = 0.f; }
#pragma unroll
  for (int st = 0; st < 16; ++st)
#pragma unroll
    for (int r = 0; r < 4; ++r) {
      float e = acc[st][r];
      l243[r] += e;
      l9[r]  += (s9[st]  == t9[r])  ? e : 0.f;
      l27[r] += (s27[st] == t27[r]) ? e : 0.f;
      l81[r] += (s81[st] == t81[r]) ? e : 0.f;
    }
#pragma unroll
  for (int r = 0; r < 4; ++r) {
#pragma unroll
    for (int d = 1; d <= 8; d <<= 1) {
      l9[r]   += __shfl_xor(l9[r], d, 64);
      l27[r]  += __shfl_xor(l27[r], d, 64);
      l81[r]  += __shfl_xor(l81[r], d, 64);
      l243[r] += __shfl_xor(l243[r], d, 64);
    }
  }
  float c0[4], c1[4], c2[4], c3[4];
#pragma unroll
  for (int r = 0; r < 4; ++r) {
    int tg = tr[r] < TT ? tr[r] : TT - 1;
    float4 g = *(const float4*)(gates + ((size_t)(b * TT + tg) * NJ + j) * 4);
    c0[r] = g.x / l9[r]; c1[r] = g.y / l27[r];
    c2[r] = g.z / l81[r]; c3[r] = g.w / l243[r];
  }
  // combined weights R -> LDS (bf16, swizzled), zero for invalid rows/cols
#pragma unroll
  for (int st = 0; st < 16; ++st) {
    int s = st * 16 + c16;
#pragma unroll
    for (int r = 0; r < 4; ++r) {
      float cw = c3[r];
      cw += (s81[st] == t81[r]) ? c2[r] : 0.f;
      cw += (s27[st] == t27[r]) ? c1[r] : 0.f;
      cw += (s9[st]  == t9[r])  ? c0[r] : 0.f;
      float rv = acc[st][r] * cw;
      if (tr[r] >= TT || s >= TT) rv = 0.f;
      int q = qw + g4 * 4 + r;
      int s8 = s >> 3;
      int slot = (s8 & 24) | ((s8 & 7) ^ (q & 7));
      L[q * 256 + slot * 8 + (s & 7)] = f2bf(rv);
    }
  }
  __syncthreads();   // R visible + V staged (barrier drains vmcnt)

  // ---- PV: O[16q][64c] = R[16][256] @ V[256][64]
  short8 ar[8];
#pragma unroll
  for (int h2 = 0; h2 < 8; ++h2) {
    int q = qw + c16;
    int c8 = h2 * 4 + g4;
    int slot = (c8 & 24) | ((c8 & 7) ^ (q & 7));
    ar[h2] = *(const short8*)(L + q * 256 + slot * 8);
  }
  f32x4 o[4];
#pragma unroll
  for (int jt = 0; jt < 4; ++jt) o[jt] = (f32x4)(0.f);
#pragma unroll
  for (int jt = 0; jt < 4; ++jt) {
    int c = jt * 16 + c16;
#pragma unroll
    for (int h2 = 0; h2 < 8; ++h2) {
      int c8 = h2 * 4 + g4;
      int slot = (c8 & 24) | ((c8 & 7) ^ (c & 7));
      short8 bv = *(const short8*)(L + 16384 + c * 256 + slot * 8);
      o[jt] = MFMA16(ar[h2], bv, o[jt]);
    }
  }
  // ---- store pre (bf16)
#pragma unroll
  for (int jt = 0; jt < 4; ++jt)
#pragma unroll
    for (int r = 0; r < 4; ++r) {
      int t = tr[r];
      if (t < TT)
        preb[((size_t)(b * TT + t) * NJ + j) * 512 + h * 64 + jt * 16 + c16] =
            f2bf(o[jt][r]);
    }
}

// ---------------- proj GEMM (bf16 MFMA) + bias, fp32 out ----------------
__global__ __launch_bounds__(256) void proj_gemm(
    const u16* __restrict__ preb, const u16* __restrict__ pwt,
    const float* __restrict__ bias, float* __restrict__ out) {
  __shared__ u16 Al[128 * 32];
  __shared__ u16 Bl[128 * 32];
  int tid = threadIdx.x;
  int w = tid >> 6, l = tid & 63;
  int c16 = tid & 15, g4 = (tid >> 4) & 3;
  int r0 = blockIdx.x * 128, n0 = blockIdx.y * 128;
  int wm = w & 1, wn = w >> 1;
  f32x4 acc[4][4] = {};
  for (int k0 = 0; k0 < CDIM; k0 += 32) {
    __syncthreads();
#pragma unroll
    for (int it = 0; it < 2; ++it) {
      int F = it * 256 + w * 64 + l;
      int row = F >> 2, c8 = F & 3;
      int gr = r0 + row; gr = gr < NROWS ? gr : NROWS - 1;
      gl_lds16(preb + (size_t)gr * 512 + k0 + c8 * 8,
               Al + (size_t)(it * 256 + w * 64) * 8);
      gl_lds16(pwt + (size_t)(n0 + row) * 512 + k0 + c8 * 8,
               Bl + (size_t)(it * 256 + w * 64) * 8);
    }
    __syncthreads();
    short8 af[4], bf[4];
#pragma unroll
    for (int i = 0; i < 4; ++i)
      af[i] = *(const short8*)(Al + ((wm * 64 + i * 16 + c16) * 32 + g4 * 8));
#pragma unroll
    for (int j = 0; j < 4; ++j)
      bf[j] = *(const short8*)(Bl + ((wn * 64 + j * 16 + c16) * 32 + g4 * 8));
#pragma unroll
    for (int i = 0; i < 4; ++i)
#pragma unroll
      for (int j = 0; j < 4; ++j)
        acc[i][j] = MFMA16(af[i], bf[j], acc[i][j]);
  }
#pragma unroll
  for (int i = 0; i < 4; ++i)
#pragma unroll
    for (int r = 0; r < 4; ++r) {
      int row = r0 + wm * 64 + i * 16 + g4 * 4 + r;
      if (row >= NROWS) continue;
#pragma unroll
      for (int jt = 0; jt < 4; ++jt) {
        int col = n0 + wn * 64 + jt * 16 + c16;
        out[(size_t)row * 512 + col] = acc[i][jt][r] + bias[col];
      }
    }
}

extern "C" void kernel_launch(void* const* d_in, const int* in_sizes, int n_in,
                              void* d_out, int out_size, void* d_ws, size_t ws_size,
                              hipStream_t stream) {
  (void)in_sizes; (void)n_in; (void)out_size; (void)ws_size;
  const float* x      = (const float*)d_in[0];
  const float* qkv_w  = (const float*)d_in[1];
  const float* proj_w = (const float*)d_in[2];
  const float* proj_b = (const float*)d_in[3];
  const float* te_w   = (const float*)d_in[4];
  const float* te_b   = (const float*)d_in[5];

  char* p = (char*)d_ws;
  auto alloc = [&](size_t bytes) {
    void* r = (void*)p;
    p += (bytes + 255) & ~(size_t)255;
    return r;
  };
  u16*   xb    = (u16*)alloc((size_t)NROWS * 512 * 2);
  u16*   wt    = (u16*)alloc((size_t)1536 * 512 * 2);
  u16*   pwt   = (u16*)alloc((size_t)512 * 512 * 2);
  float* gates = (float*)alloc((size_t)NROWS * 4 * 4);
  u16*   qkvb  = (u16*)alloc((size_t)NROWS * 1536 * 2);
  u16*   vb    = (u16*)alloc((size_t)NBHN * 64 * 256 * 2);
  u16*   preb  = (u16*)alloc((size_t)NROWS * 512 * 2);
  float* out   = (float*)d_out;

  hipLaunchKernelGGL(conv_x, dim3(NROWS * 512 / 4 / 256), dim3(256), 0, stream,
                     x, xb, NROWS * 512 / 4);
  hipLaunchKernelGGL(trans_w, dim3(48, 16), dim3(256), 0, stream,
                     qkv_w, wt, 512, 1536);
  hipLaunchKernelGGL(trans_w, dim3(16, 16), dim3(256), 0, stream,
                     proj_w, pwt, 512, 512);
  hipLaunchKernelGGL(gates_kernel, dim3((NROWS + 3) / 4), dim3(256), 0, stream,
                     x, te_w, te_b, gates);
  hipLaunchKernelGGL(qkv_gemm, dim3((NROWS + 127) / 128, 12), dim3(256), 0, stream,
                     xb, wt, qkvb, vb);
  hipLaunchKernelGGL(attn_kernel, dim3(NBHN, 4), dim3(256), 0, stream,
                     qkvb, vb, gates, preb);
  hipLaunchKernelGGL(proj_gemm, dim3((NROWS + 127) / 128, 4), dim3(256), 0, stream,
                     preb, pwt, proj_b, out);
}

// Round 4
// 241.916 us; speedup vs baseline: 17.7968x; 1.3042x over previous
//
#include <hip/hip_runtime.h>
#include <hip/hip_bf16.h>
#include <cstdint>

#define TT 243
#define NJ 17
#define NB 4
#define NH 8
#define HD 64
#define CDIM 512
#define NROWS (NB*TT*NJ)   // 16524
#define NBHN (NB*NH*NJ)    // 544

typedef unsigned short u16;
typedef __attribute__((ext_vector_type(8))) short short8;
typedef __attribute__((ext_vector_type(4))) float f32x4;

#define MFMA16(a, b, c) __builtin_amdgcn_mfma_f32_16x16x32_bf16((a), (b), (c), 0, 0, 0)

__device__ __forceinline__ void gl_lds16(const void* g, void* l) {
  __builtin_amdgcn_global_load_lds(
      (const __attribute__((address_space(1))) void*)g,
      (__attribute__((address_space(3))) void*)l, 16, 0, 0);
}

__device__ __forceinline__ u16 f2bf(float f) {
  union { float f; unsigned u; } v; v.f = f;
  unsigned r = v.u + 0x7FFFu + ((v.u >> 16) & 1u);
  return (u16)(r >> 16);
}

__device__ __forceinline__ float wave_reduce_sum(float v) {
#pragma unroll
  for (int off = 32; off > 0; off >>= 1) v += __shfl_xor(v, off, 64);
  return v;
}

// ---------------- fused: x fp32 -> bf16 copy + expert gates softmax ----------------
__global__ __launch_bounds__(256) void convgates(
    const float* __restrict__ x, const float* __restrict__ te_w,
    const float* __restrict__ te_b, u16* __restrict__ xb,
    float* __restrict__ gates) {
  int w = threadIdx.x >> 6, l = threadIdx.x & 63;
  int row = blockIdx.x * 4 + w;
  if (row >= NROWS) return;
  const float* xr = x + (size_t)row * CDIM;
  u16* xo = xb + (size_t)row * CDIM;
  float a0 = 0.f, a1 = 0.f, a2 = 0.f, a3 = 0.f;
#pragma unroll
  for (int p = 0; p < 2; ++p) {
    int c = (p * 64 + l) * 4;
    float4 v = *(const float4*)(xr + c);
    ushort4 o;
    o.x = f2bf(v.x); o.y = f2bf(v.y); o.z = f2bf(v.z); o.w = f2bf(v.w);
    *(ushort4*)(xo + c) = o;
    float xv[4] = {v.x, v.y, v.z, v.w};
#pragma unroll
    for (int q = 0; q < 4; ++q) {
      float4 wv = *(const float4*)(te_w + (size_t)(c + q) * 4);
      a0 += xv[q] * wv.x; a1 += xv[q] * wv.y;
      a2 += xv[q] * wv.z; a3 += xv[q] * wv.w;
    }
  }
  a0 = wave_reduce_sum(a0);
  a1 = wave_reduce_sum(a1);
  a2 = wave_reduce_sum(a2);
  a3 = wave_reduce_sum(a3);
  a0 += te_b[0]; a1 += te_b[1]; a2 += te_b[2]; a3 += te_b[3];
  float mx = fmaxf(fmaxf(a0, a1), fmaxf(a2, a3));
  float e0 = __expf(a0 - mx), e1 = __expf(a1 - mx);
  float e2 = __expf(a2 - mx), e3 = __expf(a3 - mx);
  float inv = 1.f / (e0 + e1 + e2 + e3);
  if (l == 0) {
    *(float4*)(gates + (size_t)row * 4) =
        make_float4(e0 * inv, e1 * inv, e2 * inv, e3 * inv);
  }
}

// ---------------- prep: transpose fp32 [K][N] -> bf16 [N][K] ----------------
__global__ __launch_bounds__(256) void trans_w(const float* __restrict__ in,
                                               u16* __restrict__ out, int K, int N) {
  __shared__ float tile[32][33];
  int n0 = blockIdx.x * 32, k0 = blockIdx.y * 32;
  int tx = threadIdx.x & 31, ty = threadIdx.x >> 5;
#pragma unroll
  for (int p = 0; p < 4; ++p)
    tile[ty + p * 8][tx] = in[(size_t)(k0 + ty + p * 8) * N + n0 + tx];
  __syncthreads();
#pragma unroll
  for (int p = 0; p < 4; ++p)
    out[(size_t)(n0 + ty + p * 8) * K + k0 + tx] = f2bf(tile[tx][ty + p * 8]);
}

// ---------------- qkv GEMM (bf16 MFMA), M permuted to (b,j,t) ----------------
// q -> qh[bhn][243][64], k -> kh[bhn][243][64], v -> vb[bhn][64][256] (t-contig via LDS transpose)
__global__ __launch_bounds__(256) void qkv_gemm(
    const u16* __restrict__ xb, const u16* __restrict__ wt,
    u16* __restrict__ qh, u16* __restrict__ kh, u16* __restrict__ vb) {
  __shared__ u16 S[16640];   // union: Al [0,8192) + Bl [8192,16384) | T [0,16640) stride 130
  u16* Al = S;
  u16* Bl = S + 8192;
  int tid = threadIdx.x;
  int w = tid >> 6, l = tid & 63;
  int c16 = tid & 15, g4 = (tid >> 4) & 3;
  int r0 = blockIdx.x * 128, n0 = blockIdx.y * 128;
  int wm = w & 1, wn = w >> 1;

  // precompute permuted-row source addresses for this thread's 2 A-chunks
  size_t arow[2]; int ac8[2], brow[2];
#pragma unroll
  for (int it = 0; it < 2; ++it) {
    int F = it * 256 + w * 64 + l;
    int row = F >> 2;
    ac8[it] = F & 3;
    brow[it] = n0 + row;
    int m = r0 + row; if (m >= NROWS) m = NROWS - 1;
    int bj = m / 243, t = m - bj * 243;
    int b = bj / 17, j = bj - b * 17;
    arow[it] = ((size_t)(b * 243 + t) * 17 + j) * 512;
  }

  f32x4 acc[4][4] = {};
  for (int k0 = 0; k0 < CDIM; k0 += 32) {
    __syncthreads();
#pragma unroll
    for (int it = 0; it < 2; ++it) {
      gl_lds16(xb + arow[it] + k0 + ac8[it] * 8,
               Al + (size_t)(it * 256 + w * 64) * 8);
      gl_lds16(wt + (size_t)brow[it] * 512 + k0 + ac8[it] * 8,
               Bl + (size_t)(it * 256 + w * 64) * 8);
    }
    __syncthreads();
    short8 af[4], bf[4];
#pragma unroll
    for (int i = 0; i < 4; ++i)
      af[i] = *(const short8*)(Al + ((wm * 64 + i * 16 + c16) * 32 + g4 * 8));
#pragma unroll
    for (int j = 0; j < 4; ++j)
      bf[j] = *(const short8*)(Bl + ((wn * 64 + j * 16 + c16) * 32 + g4 * 8));
#pragma unroll
    for (int i = 0; i < 4; ++i)
#pragma unroll
      for (int j = 0; j < 4; ++j)
        acc[i][j] = MFMA16(af[i], bf[j], acc[i][j]);
  }

  if (n0 < 1024) {
    // ---- q/k epilogue: direct store to [bhn][t][64]
#pragma unroll
    for (int i = 0; i < 4; ++i)
#pragma unroll
      for (int r = 0; r < 4; ++r) {
        int m = r0 + wm * 64 + i * 16 + g4 * 4 + r;
        if (m >= NROWS) continue;
        int bj = m / 243, t = m - bj * 243;
        int b = bj / 17, j = bj - b * 17;
#pragma unroll
        for (int jt = 0; jt < 4; ++jt) {
          int col = n0 + wn * 64 + jt * 16 + c16;
          int sel = col >> 9, h = (col >> 6) & 7, c = col & 63;
          u16* dst = sel ? kh : qh;
          dst[((size_t)((b * 8 + h) * 17 + j) * 243 + t) * 64 + c] =
              f2bf(acc[i][jt][r]);
        }
      }
  } else {
    // ---- V epilogue: transpose C-tile via LDS, store t-contiguous
    __syncthreads();  // all waves done reading Al/Bl
#pragma unroll
    for (int i = 0; i < 4; ++i)
#pragma unroll
      for (int jt = 0; jt < 4; ++jt)
#pragma unroll
        for (int r = 0; r < 4; ++r) {
          int row = wm * 64 + i * 16 + g4 * 4 + r;
          int colI = wn * 64 + jt * 16 + c16;
          S[colI * 130 + row] = f2bf(acc[i][jt][r]);
        }
    __syncthreads();
    int hb = (n0 - 1024) >> 6;
    int m0 = r0 + 2 * l;
    int m1 = m0 + 1;
    bool v0 = m0 < NROWS, v1 = m1 < NROWS;
    int bj0 = m0 / 243, t0 = m0 - bj0 * 243;
    int b0 = bj0 / 17, j0 = bj0 - b0 * 17;
    int bj1 = m1 / 243, t1 = m1 - bj1 * 243;
    int b1 = bj1 / 17, j1 = bj1 - b1 * 17;
    size_t base0 = ((size_t)(b0 * 136 + j0) * 64) * 256 + t0;  // + (h*17)*64*256 + c*256
    size_t base1 = ((size_t)(b1 * 136 + j1) * 64) * 256 + t1;
#pragma unroll 8
    for (int cc = 0; cc < 32; ++cc) {
      int colI = w * 32 + cc;
      int h = hb + (colI >> 6), c = colI & 63;
      ushort2 u = *(const ushort2*)&S[colI * 130 + 2 * l];
      size_t hoff = ((size_t)h * 17 * 64) * 256 + (size_t)c * 256;
      if (v0) vb[base0 + hoff] = u.x;
      if (v1) vb[base1 + hoff] = u.y;
    }
  }
}

// ---------------- fused attention (bf16 MFMA) ----------------
// grid (544, 4): one (b,h,j), 64-query tile. LDS 64KB union:
//  phase1: K [0,16384) elems [256][64] swizzled; Q [16384,20480) [64][64] swizzled
//  phase2: R [0,16384) [64][256] swizzled;      V [16384,32768) [64][256] swizzled
__global__ __launch_bounds__(256) void attn_kernel(
    const u16* __restrict__ qh, const u16* __restrict__ kh,
    const u16* __restrict__ vb, const float* __restrict__ gates,
    u16* __restrict__ preb) {
  __shared__ u16 L[32768];
  int bhn = blockIdx.x;
  int q0 = blockIdx.y * 64;
  int b = bhn / (NH * NJ);
  int hj = bhn - b * (NH * NJ);
  int h = hj / NJ, j = hj - (hj / NJ) * NJ;
  int tid = threadIdx.x;
  int w = tid >> 6, l = tid & 63;
  int c16 = tid & 15, g4 = (tid >> 4) & 3;
  int qw = w * 16;

  // ---- stage K (8 calls) + Q (2 calls), xor-swizzled chunks
#pragma unroll
  for (int it = 0; it < 8; ++it) {
    int F = it * 256 + w * 64 + l;          // 0..2047
    int s = F >> 3;
    int c8 = (F & 7) ^ (s & 7);
    int sg = s < TT ? s : TT - 1;
    gl_lds16(kh + ((size_t)bhn * 243 + sg) * 64 + c8 * 8,
             L + (size_t)(it * 256 + w * 64) * 8);
  }
#pragma unroll
  for (int it = 0; it < 2; ++it) {
    int F = it * 256 + w * 64 + l;          // 0..511
    int q = F >> 3;
    int c8 = (F & 7) ^ (q & 7);
    int t = q0 + q; int tg = t < TT ? t : TT - 1;
    gl_lds16(qh + ((size_t)bhn * 243 + tg) * 64 + c8 * 8,
             L + 16384 + (size_t)(it * 256 + w * 64) * 8);
  }
  __syncthreads();

  // ---- scores: S[16q][256s] per wave, C-fragments
  short8 aq[2];
#pragma unroll
  for (int hh = 0; hh < 2; ++hh) {
    int q = qw + c16;
    aq[hh] = *(const short8*)(L + 16384 + q * 64 + ((hh * 4 + g4) ^ (q & 7)) * 8);
  }
  f32x4 acc[16];
#pragma unroll
  for (int st = 0; st < 16; ++st) acc[st] = (f32x4)(0.f);
#pragma unroll
  for (int st = 0; st < 16; ++st) {
    int s = st * 16 + c16;
#pragma unroll
    for (int hh = 0; hh < 2; ++hh) {
      short8 bk = *(const short8*)(L + s * 64 + ((hh * 4 + g4) ^ (s & 7)) * 8);
      acc[st] = MFMA16(aq[hh], bk, acc[st]);
    }
  }
  __syncthreads();   // all K/Q reads complete before LDS reuse

  // ---- stage V [64c][256s] into upper half (overlaps softmax below)
#pragma unroll
  for (int it = 0; it < 8; ++it) {
    int F = it * 256 + w * 64 + l;          // 0..2047
    int c = F >> 5;
    int slot = F & 31;
    int c8 = (slot & 24) | ((slot & 7) ^ (c & 7));
    gl_lds16(vb + ((size_t)bhn * 64 + c) * 256 + c8 * 8,
             L + 16384 + (size_t)(it * 256 + w * 64) * 8);
  }

  // ---- softmax over nested windows, in registers
  int tr[4], t9[4], t27[4], t81[4];
#pragma unroll
  for (int r = 0; r < 4; ++r) {
    tr[r] = q0 + qw + g4 * 4 + r;
    t9[r] = tr[r] / 9; t27[r] = t9[r] / 3; t81[r] = t27[r] / 3;
  }
#pragma unroll
  for (int st = 0; st < 16; ++st) {
    int s = st * 16 + c16;
#pragma unroll
    for (int r = 0; r < 4; ++r) {
      float v = acc[st][r] * 0.125f;
      acc[st][r] = (s < TT) ? v : -1e30f;
    }
  }
  float M[4];
#pragma unroll
  for (int r = 0; r < 4; ++r) {
    float m = -1e30f;
#pragma unroll
    for (int st = 0; st < 16; ++st) m = fmaxf(m, acc[st][r]);
    m = fmaxf(m, __shfl_xor(m, 1, 64));
    m = fmaxf(m, __shfl_xor(m, 2, 64));
    m = fmaxf(m, __shfl_xor(m, 4, 64));
    m = fmaxf(m, __shfl_xor(m, 8, 64));
    M[r] = m;
  }
#pragma unroll
  for (int st = 0; st < 16; ++st)
#pragma unroll
    for (int r = 0; r < 4; ++r) acc[st][r] = __expf(acc[st][r] - M[r]);
  int s9[16], s27[16], s81[16];
#pragma unroll
  for (int st = 0; st < 16; ++st) {
    int s = st * 16 + c16;
    s9[st] = s / 9; s27[st] = s9[st] / 3; s81[st] = s27[st] / 3;
  }
  float l9[4], l27[4], l81[4], l243[4];
#pragma unroll
  for (int r = 0; r < 4; ++r) { l9[r] = 0.f; l27[r] = 0.f; l81[r] = 0.f; l243[r] = 0.f; }
#pragma unroll
  for (int st = 0; st < 16; ++st)
#pragma unroll
    for (int r = 0; r < 4; ++r) {
      float e = acc[st][r];
      l243[r] += e;
      l9[r]  += (s9[st]  == t9[r])  ? e : 0.f;
      l27[r] += (s27[st] == t27[r]) ? e : 0.f;
      l81[r] += (s81[st] == t81[r]) ? e : 0.f;
    }
#pragma unroll
  for (int r = 0; r < 4; ++r) {
#pragma unroll
    for (int d = 1; d <= 8; d <<= 1) {
      l9[r]   += __shfl_xor(l9[r], d, 64);
      l27[r]  += __shfl_xor(l27[r], d, 64);
      l81[r]  += __shfl_xor(l81[r], d, 64);
      l243[r] += __shfl_xor(l243[r], d, 64);
    }
  }
  float c0[4], c1[4], c2[4], c3[4];
#pragma unroll
  for (int r = 0; r < 4; ++r) {
    int tg = tr[r] < TT ? tr[r] : TT - 1;
    float4 g = *(const float4*)(gates + ((size_t)(b * TT + tg) * NJ + j) * 4);
    c0[r] = g.x / l9[r]; c1[r] = g.y / l27[r];
    c2[r] = g.z / l81[r]; c3[r] = g.w / l243[r];
  }
#pragma unroll
  for (int st = 0; st < 16; ++st) {
    int s = st * 16 + c16;
#pragma unroll
    for (int r = 0; r < 4; ++r) {
      float cw = c3[r];
      cw += (s81[st] == t81[r]) ? c2[r] : 0.f;
      cw += (s27[st] == t27[r]) ? c1[r] : 0.f;
      cw += (s9[st]  == t9[r])  ? c0[r] : 0.f;
      float rv = acc[st][r] * cw;
      if (tr[r] >= TT || s >= TT) rv = 0.f;
      int q = qw + g4 * 4 + r;
      int s8 = s >> 3;
      int slot = (s8 & 24) | ((s8 & 7) ^ (q & 7));
      L[q * 256 + slot * 8 + (s & 7)] = f2bf(rv);
    }
  }
  __syncthreads();   // R visible + V staged (barrier drains vmcnt)

  // ---- PV: O[16q][64c] = R[16][256] @ V[256][64]
  short8 ar[8];
#pragma unroll
  for (int h2 = 0; h2 < 8; ++h2) {
    int q = qw + c16;
    int c8 = h2 * 4 + g4;
    int slot = (c8 & 24) | ((c8 & 7) ^ (q & 7));
    ar[h2] = *(const short8*)(L + q * 256 + slot * 8);
  }
  f32x4 o[4];
#pragma unroll
  for (int jt = 0; jt < 4; ++jt) o[jt] = (f32x4)(0.f);
#pragma unroll
  for (int jt = 0; jt < 4; ++jt) {
    int c = jt * 16 + c16;
#pragma unroll
    for (int h2 = 0; h2 < 8; ++h2) {
      int c8 = h2 * 4 + g4;
      int slot = (c8 & 24) | ((c8 & 7) ^ (c & 7));
      short8 bv = *(const short8*)(L + 16384 + c * 256 + slot * 8);
      o[jt] = MFMA16(ar[h2], bv, o[jt]);
    }
  }
#pragma unroll
  for (int jt = 0; jt < 4; ++jt)
#pragma unroll
    for (int r = 0; r < 4; ++r) {
      int t = tr[r];
      if (t < TT)
        preb[((size_t)(b * TT + t) * NJ + j) * 512 + h * 64 + jt * 16 + c16] =
            f2bf(o[jt][r]);
    }
}

// ---------------- proj GEMM (bf16 MFMA) + bias, fp32 out ----------------
__global__ __launch_bounds__(256) void proj_gemm(
    const u16* __restrict__ preb, const u16* __restrict__ pwt,
    const float* __restrict__ bias, float* __restrict__ out) {
  __shared__ u16 Al[128 * 32];
  __shared__ u16 Bl[128 * 32];
  int tid = threadIdx.x;
  int w = tid >> 6, l = tid & 63;
  int c16 = tid & 15, g4 = (tid >> 4) & 3;
  int r0 = blockIdx.x * 128, n0 = blockIdx.y * 128;
  int wm = w & 1, wn = w >> 1;
  f32x4 acc[4][4] = {};
  for (int k0 = 0; k0 < CDIM; k0 += 32) {
    __syncthreads();
#pragma unroll
    for (int it = 0; it < 2; ++it) {
      int F = it * 256 + w * 64 + l;
      int row = F >> 2, c8 = F & 3;
      int gr = r0 + row; gr = gr < NROWS ? gr : NROWS - 1;
      gl_lds16(preb + (size_t)gr * 512 + k0 + c8 * 8,
               Al + (size_t)(it * 256 + w * 64) * 8);
      gl_lds16(pwt + (size_t)(n0 + row) * 512 + k0 + c8 * 8,
               Bl + (size_t)(it * 256 + w * 64) * 8);
    }
    __syncthreads();
    short8 af[4], bf[4];
#pragma unroll
    for (int i = 0; i < 4; ++i)
      af[i] = *(const short8*)(Al + ((wm * 64 + i * 16 + c16) * 32 + g4 * 8));
#pragma unroll
    for (int j = 0; j < 4; ++j)
      bf[j] = *(const short8*)(Bl + ((wn * 64 + j * 16 + c16) * 32 + g4 * 8));
#pragma unroll
    for (int i = 0; i < 4; ++i)
#pragma unroll
      for (int j = 0; j < 4; ++j)
        acc[i][j] = MFMA16(af[i], bf[j], acc[i][j]);
  }
#pragma unroll
  for (int i = 0; i < 4; ++i)
#pragma unroll
    for (int r = 0; r < 4; ++r) {
      int row = r0 + wm * 64 + i * 16 + g4 * 4 + r;
      if (row >= NROWS) continue;
#pragma unroll
      for (int jt = 0; jt < 4; ++jt) {
        int col = n0 + wn * 64 + jt * 16 + c16;
        out[(size_t)row * 512 + col] = acc[i][jt][r] + bias[col];
      }
    }
}

extern "C" void kernel_launch(void* const* d_in, const int* in_sizes, int n_in,
                              void* d_out, int out_size, void* d_ws, size_t ws_size,
                              hipStream_t stream) {
  (void)in_sizes; (void)n_in; (void)out_size; (void)ws_size;
  const float* x      = (const float*)d_in[0];
  const float* qkv_w  = (const float*)d_in[1];
  const float* proj_w = (const float*)d_in[2];
  const float* proj_b = (const float*)d_in[3];
  const float* te_w   = (const float*)d_in[4];
  const float* te_b   = (const float*)d_in[5];

  char* p = (char*)d_ws;
  auto alloc = [&](size_t bytes) {
    void* r = (void*)p;
    p += (bytes + 255) & ~(size_t)255;
    return r;
  };
  u16*   xb    = (u16*)alloc((size_t)NROWS * 512 * 2);
  u16*   wt    = (u16*)alloc((size_t)1536 * 512 * 2);
  u16*   pwt   = (u16*)alloc((size_t)512 * 512 * 2);
  float* gates = (float*)alloc((size_t)NROWS * 4 * 4);
  u16*   qhb   = (u16*)alloc((size_t)NBHN * 243 * 64 * 2);
  u16*   khb   = (u16*)alloc((size_t)NBHN * 243 * 64 * 2);
  u16*   vb    = (u16*)alloc((size_t)NBHN * 64 * 256 * 2);
  u16*   preb  = (u16*)alloc((size_t)NROWS * 512 * 2);
  float* out   = (float*)d_out;

  hipLaunchKernelGGL(convgates, dim3((NROWS + 3) / 4), dim3(256), 0, stream,
                     x, te_w, te_b, xb, gates);
  hipLaunchKernelGGL(trans_w, dim3(48, 16), dim3(256), 0, stream,
                     qkv_w, wt, 512, 1536);
  hipLaunchKernelGGL(trans_w, dim3(16, 16), dim3(256), 0, stream,
                     proj_w, pwt, 512, 512);
  hipLaunchKernelGGL(qkv_gemm, dim3((NROWS + 127) / 128, 12), dim3(256), 0, stream,
                     xb, wt, qhb, khb, vb);
  hipLaunchKernelGGL(attn_kernel, dim3(NBHN, 4), dim3(256), 0, stream,
                     qhb, khb, vb, gates, preb);
  hipLaunchKernelGGL(proj_gemm, dim3((NROWS + 127) / 128, 4), dim3(256), 0, stream,
                     preb, pwt, proj_b, out);
}